// Round 5
// baseline (158.073 us; speedup 1.0000x reference)
//
#include <hip/hip_runtime.h>

// Problem constants (fixed by the reference)
#define NN 512
#define KK 17
#define WW 48
#define HH 64
#define HW (WW * HH)          // 3072 pixels per (n,k)
#define NK (NN * KK)          // 8704 items
#define GRID (NN * 2)        // 2 blocks per sample (item-split) = 16 waves/CU
//
// ===== A/B history (this session) — do NOT re-try these =====
//  R2: 2048 blocks x 192 thr (ROW-quartering, 24 waves/CU, 3-deep nt
//      pipeline): 156 -> 163 us. Quartering the 51 KB slab into 3 KB
//      chunks at 12 KB stride hurt DRAM locality; 2.3x redundant staging.
//  R3: fused last-block reduction via agent-scope release store +
//      acq-rel counter: 156 -> 178 us. Agent-scope release on gfx950
//      (non-coherent per-XCD L2s) triggers L2 writeback machinery per
//      block. Keep the two-kernel structure.
//  R4: pure revert to 512x256 anchor: 155.5 us (reproduces 155.95/154.8).
//  R5 (this): ITEM-split, 2 blocks/sample: each block streams ~104 KB
//      CONTIGUOUS (unlike R2), 16 waves/CU, staging halves per block.
//      Isolates "more TLP with intact contiguity". Neutral result here
//      => partial kernel is at its BW/overhead floor => ROOFLINE.
// ============================================================

// Native clang vector type — required by __builtin_nontemporal_load
// (HIP's float4 is a class and is rejected).
typedef float fv4 __attribute__((ext_vector_type(4)));

// Loss = mean over [N,K,H,W] of (tw*mask * (g - teacher))^2, g separable:
// g = ex[w]*ey[h]. Stage ex (fv4) + ey for this block's items in LDS,
// then stream the teacher slab with a 1-deep register pipeline
// (3 outstanding 16 B nt loads/thread).
// Teacher reads use NONTEMPORAL loads: the harness leaves the cache
// hierarchy full of dirty 0xAA poison lines (428 MB d_ws fill) every
// timed iteration; regular reads evict them -> victim writebacks contend
// with our reads. nt streaming loads skip the allocation.

__global__ __launch_bounds__(256) void reg2hm_partial_kernel(
    const float* __restrict__ pred,      // [N,K,2]
    const float* __restrict__ sigma,     // [N,K,2]
    const float* __restrict__ teacher,   // [N,K,H,W]
    const float* __restrict__ twgt,      // [N,K,1]
    float* __restrict__ ws)              // [GRID] partial sums
{
    __shared__ fv4   ex4[KK][WW / 4];    // 17 x 12 fv4 (only k0..k1 used)
    __shared__ float eys[KK][HH];        // 17 x 64    (only k0..k1 used)
    __shared__ float sw[KK];
    __shared__ float wave_sums[4];

    const int b    = blockIdx.x;
    const int n    = b >> 1;             // sample
    const int half = b & 1;              // item half: 0 -> [0,9), 1 -> [9,17)
    const int k0   = half ? 9 : 0;
    const int k1   = half ? KK : 9;
    const int nit  = k1 - k0;            // 9 or 8 items
    const int nk0  = n * KK;
    const int t    = threadIdx.x;

    // Per-item weight (mask * target_weight) — all 17, trivial.
    if (t < KK) {
        const int nk = nk0 + t;
        const float mu_x = pred[nk * 2 + 0] * (float)WW;
        const float mu_y = pred[nk * 2 + 1] * (float)HH;
        const float sx   = sigma[nk * 2 + 0];
        const float sy   = sigma[nk * 2 + 1];
        const bool m = (mu_x - 3.0f * sx < (float)WW) &&
                       (mu_y - 3.0f * sy < (float)HH) &&
                       (mu_x + 3.0f * sx + 1.0f >= 0.0f) &&
                       (mu_y + 3.0f * sy + 1.0f >= 0.0f);
        sw[t] = twgt[nk] * (m ? 1.0f : 0.0f);
    }

    // Stage separable exponentials for THIS block's items:
    // nit*(48+64) = 1008 or 896 entries.
    float* exf = (float*)ex4;
    for (int i = t; i < nit * (WW + HH); i += 256) {
        const int item = k0 + i / (WW + HH);
        const int r    = i - (item - k0) * (WW + HH);
        const int nk   = nk0 + item;
        if (r < WW) {
            const float mu = pred[nk * 2 + 0] * (float)WW;
            const float s  = sigma[nk * 2 + 0];
            const float d  = (float)r - mu;
            exf[item * WW + r] = __expf(-d * d * (0.5f / (s * s + 1e-9f)));
        } else {
            const float mu = pred[nk * 2 + 1] * (float)HH;
            const float s  = sigma[nk * 2 + 1];
            const float d  = (float)(r - WW) - mu;
            eys[item][r - WW] = __expf(-d * d * (0.5f / (s * s + 1e-9f)));
        }
    }
    __syncthreads();

    // Item-invariant index math: fv4 index i in [0,768), h = i/12, s = i%12.
    const int i0 = t;
    const int i1 = t + 256;
    const int i2 = t + 512;
    const int h0 = i0 / 12, s0 = i0 - h0 * 12;
    const int h1 = i1 / 12, s1 = i1 - h1 * 12;
    const int h2 = i2 / 12, s2 = i2 - h2 * 12;

    const fv4* tp = (const fv4*)(teacher + (size_t)nk0 * HW);

    // 1-deep software pipeline over this block's items (768 fv4 each),
    // all teacher reads nontemporal (streaming, no cache allocation).
    fv4 c0 = __builtin_nontemporal_load(tp + k0 * (HW / 4) + i0);
    fv4 c1 = __builtin_nontemporal_load(tp + k0 * (HW / 4) + i1);
    fv4 c2 = __builtin_nontemporal_load(tp + k0 * (HW / 4) + i2);
    float total = 0.0f;
#pragma unroll 1
    for (int item = k0; item < k1; ++item) {
        fv4 n0, n1, n2;
        if (item + 1 < k1) {
            const fv4* np_ = tp + (item + 1) * (HW / 4);
            n0 = __builtin_nontemporal_load(np_ + i0);
            n1 = __builtin_nontemporal_load(np_ + i1);
            n2 = __builtin_nontemporal_load(np_ + i2);
        }
        const fv4   e0 = ex4[item][s0];
        const fv4   e1 = ex4[item][s1];
        const fv4   e2 = ex4[item][s2];
        const float y0 = eys[item][h0];
        const float y1 = eys[item][h1];
        const float y2 = eys[item][h2];

        float acc = 0.0f;
        {
            const fv4 d = e0 * y0 - c0;
            acc += d.x * d.x + d.y * d.y + d.z * d.z + d.w * d.w;
        }
        {
            const fv4 d = e1 * y1 - c1;
            acc += d.x * d.x + d.y * d.y + d.z * d.z + d.w * d.w;
        }
        {
            const fv4 d = e2 * y2 - c2;
            acc += d.x * d.x + d.y * d.y + d.z * d.z + d.w * d.w;
        }
        total += sw[item] * sw[item] * acc;
        c0 = n0; c1 = n1; c2 = n2;
    }

    // Wave(64) shuffle reduction, then cross-wave via LDS.
#pragma unroll
    for (int off = 32; off > 0; off >>= 1)
        total += __shfl_down(total, off, 64);

    const int wave = t >> 6;
    const int lane = t & 63;
    if (lane == 0) wave_sums[wave] = total;
    __syncthreads();

    if (t == 0)
        ws[b] = wave_sums[0] + wave_sums[1] + wave_sums[2] + wave_sums[3];
}

__global__ __launch_bounds__(256) void reg2hm_final_kernel(
    const float* __restrict__ ws, float* __restrict__ out)
{
    __shared__ float wave_sums[4];
    const int t = threadIdx.x;
    float sum = 0.0f;
    for (int i = t; i < GRID; i += 256) sum += ws[i];
#pragma unroll
    for (int off = 32; off > 0; off >>= 1)
        sum += __shfl_down(sum, off, 64);
    const int wave = t >> 6;
    const int lane = t & 63;
    if (lane == 0) wave_sums[wave] = sum;
    __syncthreads();
    if (t == 0) {
        const float total = wave_sums[0] + wave_sums[1] + wave_sums[2] + wave_sums[3];
        out[0] = total * (1.0f / ((float)NN * KK * HW));
    }
}

extern "C" void kernel_launch(void* const* d_in, const int* in_sizes, int n_in,
                              void* d_out, int out_size, void* d_ws, size_t ws_size,
                              hipStream_t stream) {
    const float* pred    = (const float*)d_in[0];
    const float* sigma   = (const float*)d_in[1];
    const float* teacher = (const float*)d_in[2];
    const float* twgt    = (const float*)d_in[3];
    float* out = (float*)d_out;
    float* ws  = (float*)d_ws;   // needs GRID*4 = 4096 bytes

    reg2hm_partial_kernel<<<GRID, 256, 0, stream>>>(pred, sigma, teacher, twgt, ws);
    reg2hm_final_kernel<<<1, 256, 0, stream>>>(ws, out);
}